// Round 12
// baseline (175.655 us; speedup 1.0000x reference)
//
#include <hip/hip_runtime.h>
#include <stdint.h>

typedef unsigned short u16;
typedef __bf16 bf16x8 __attribute__((ext_vector_type(8)));
typedef unsigned short u16x8 __attribute__((ext_vector_type(8)));
typedef float f32x4 __attribute__((ext_vector_type(4)));

#define LOG2E 1.4426950408889634f

typedef const __attribute__((address_space(1))) uint32_t as1_u32;
typedef __attribute__((address_space(3))) uint32_t as3_u32;

// float -> bf16 round-to-nearest-even
__device__ __forceinline__ u16 f2bf(float f) {
  union { float f; uint32_t i; } v; v.f = f;
  uint32_t r = (v.i + 0x7fffu + ((v.i >> 16) & 1u)) >> 16;
  return (u16)r;
}
__device__ __forceinline__ float bf2f(u16 u) {
  union { uint32_t i; float f; } v; v.i = ((uint32_t)u) << 16; return v.f;
}

__device__ __forceinline__ void gld_lds16(const void* g, void* l) {
  as1_u32* gp = (as1_u32*)((uintptr_t)g);
  as3_u32* lp = (as3_u32*)(uint32_t)(uintptr_t)(l);
  __builtin_amdgcn_global_load_lds(gp, lp, 16, 0, 0);
}

// ---------------------------------------------------------------------------
// Kernel 0: f32 -> bf16 convert.
// ---------------------------------------------------------------------------
__global__ __launch_bounds__(256) void f32_to_bf16(
    const float* __restrict__ x, const float* __restrict__ wq,
    const float* __restrict__ wk, const float* __restrict__ wv,
    u16* __restrict__ xc, u16* __restrict__ wqc,
    u16* __restrict__ wkc, u16* __restrict__ wvc) {
  const int z = blockIdx.y;
  const float* src = z == 0 ? x : (z == 1 ? wq : (z == 2 ? wk : wv));
  u16* dst = z == 0 ? xc : (z == 1 ? wqc : (z == 2 ? wkc : wvc));
  const int n = z == 0 ? (1 << 22) : (1 << 20);

  const int idx = (blockIdx.x * 256 + (int)threadIdx.x) * 8;
  if (idx >= n) return;
  const f32x4 a = *(const f32x4*)&src[idx];
  const f32x4 b = *(const f32x4*)&src[idx + 4];
  u16x8 o;
#pragma unroll
  for (int j = 0; j < 4; j++) { o[j] = f2bf(a[j]); o[j + 4] = f2bf(b[j]); }
  *(u16x8*)&dst[idx] = o;
}

// ---------------------------------------------------------------------------
// Kernel 1: QKV GEMM (unchanged from R11 — control).
// ---------------------------------------------------------------------------
__global__ __launch_bounds__(256) void qkv_gemm(
    const u16* __restrict__ xc, const u16* __restrict__ wqc,
    const u16* __restrict__ wkc, const u16* __restrict__ wvc,
    u16* __restrict__ qo, u16* __restrict__ ko, u16* __restrict__ vt) {
  __shared__ __align__(16) u16 As[128 * 32];
  __shared__ __align__(16) u16 Bs[128 * 32];

  const int tid = threadIdx.x;
  const int lane = tid & 63;
  const int w = tid >> 6;
  const int wm = w >> 1, wn = w & 1;
  const int quad = lane >> 4, m16 = lane & 15;
  const int which = blockIdx.z;

  const u16* __restrict__ Ap;
  const u16* __restrict__ Bp;
  int m0, n0;
  if (which == 2) {
    Ap = wvc; Bp = xc;
    m0 = blockIdx.x * 128;
    n0 = blockIdx.y * 128;
  } else {
    Ap = xc; Bp = which == 0 ? wqc : wkc;
    m0 = blockIdx.y * 128;
    n0 = blockIdx.x * 128;
  }

  const f32x4 z4 = {0.f, 0.f, 0.f, 0.f};
  f32x4 acc[4][4];
#pragma unroll
  for (int i = 0; i < 4; i++)
#pragma unroll
    for (int j = 0; j < 4; j++) acc[i][j] = z4;

  const int rowA = m0 + w * 32 + (lane >> 2);
  const int rowB = n0 + w * 32 + (lane >> 2);
  const int cch = (lane & 3) * 8;

  for (int k0 = 0; k0 < 1024; k0 += 32) {
    __syncthreads();
#pragma unroll
    for (int i = 0; i < 2; i++) {
      gld_lds16(&Ap[(size_t)(rowA + i * 16) * 1024 + k0 + cch],
                &As[(w * 32 + i * 16) * 32]);
      gld_lds16(&Bp[(size_t)(rowB + i * 16) * 1024 + k0 + cch],
                &Bs[(w * 32 + i * 16) * 32]);
    }
    __syncthreads();

    bf16x8 af[4], bfr[4];
#pragma unroll
    for (int t = 0; t < 4; t++) {
      af[t]  = *(const bf16x8*)&As[(wm * 64 + t * 16 + m16) * 32 + quad * 8];
      bfr[t] = *(const bf16x8*)&Bs[(wn * 64 + t * 16 + m16) * 32 + quad * 8];
    }
#pragma unroll
    for (int mt = 0; mt < 4; mt++)
#pragma unroll
      for (int nt = 0; nt < 4; nt++)
        acc[mt][nt] = __builtin_amdgcn_mfma_f32_16x16x32_bf16(
            af[mt], bfr[nt], acc[mt][nt], 0, 0, 0);
  }

  if (which < 2) {
    u16* __restrict__ out = which == 0 ? qo : ko;
#pragma unroll
    for (int mt = 0; mt < 4; mt++) {
      const int row = m0 + wm * 64 + mt * 16 + quad * 4;
#pragma unroll
      for (int nt = 0; nt < 4; nt++) {
        const int n = n0 + wn * 64 + nt * 16 + m16;
        f32x4 a = acc[mt][nt];
#pragma unroll
        for (int r = 0; r < 4; r++)
          out[(size_t)(row + r) * 1024 + n] = f2bf(a[r]);
      }
    }
  } else {
#pragma unroll
    for (int mt = 0; mt < 4; mt++) {
      const int row = m0 + wm * 64 + mt * 16 + quad * 4;
#pragma unroll
      for (int nt = 0; nt < 4; nt++) {
        const int n = n0 + wn * 64 + nt * 16 + m16;
        f32x4 a = acc[mt][nt];
#pragma unroll
        for (int r = 0; r < 4; r++)
          vt[(size_t)(row + r) * 4096 + n] = f2bf(a[r]);
      }
    }
  }
}

// ---------------------------------------------------------------------------
// Kernel 2: RoPE, K only (q-rope is fused into flash's Q-fragment load).
// ---------------------------------------------------------------------------
__global__ __launch_bounds__(256) void rope_inplace_k(u16* __restrict__ kb) {
  const int p = blockIdx.x * 256 + (int)threadIdx.x;
  const int nidx = p * 2;
  const int row = nidx >> 10;
  const int col = nidx & 1023;
  const int i = (col & 63) >> 1;
  const int t = row & 2047;
  const float theta = exp2f(-(float)i * 0.02595256324130752f);
  const float ang = (float)t * theta;
  float s, c;
  sincosf(ang, &s, &c);
  const float a0 = bf2f(kb[(size_t)row * 1024 + col]);
  const float a1 = bf2f(kb[(size_t)row * 1024 + col + 1]);
  kb[(size_t)row * 1024 + col]     = f2bf(a0 * c - a1 * s);
  kb[(size_t)row * 1024 + col + 1] = f2bf(a1 * c + a0 * s);
}

// ---------------------------------------------------------------------------
// Kernel 3: causal flash attention, K-SPLIT: 512 thr / 8 waves.
// Waves 0-3 (grp0) process even k-tiles, waves 4-7 (grp1) odd k-tiles —
// additive O/l combine at pass end (valid because no-rescale softmax).
// Q A-frags loaded direct from global with fused q-RoPE (no Qs LDS).
// Pair-balanced: block x runs qt=x then qt=31-x (33 tiles total).
// ---------------------------------------------------------------------------
__global__ __launch_bounds__(512) void flash_attn(
    const u16* __restrict__ qg, const u16* __restrict__ kg,
    const u16* __restrict__ vt, float* __restrict__ out) {
  __shared__ __align__(16) u16 Ks[2 * 64 * 72];
  __shared__ __align__(16) u16 Vs[2 * 64 * 72];
  __shared__ __align__(16) u16 Ps[2 * 64 * 72];

  const int tid = threadIdx.x, lane = tid & 63, w = tid >> 6;
  const int grp = w >> 2, wl = w & 3;
  const int quad = lane >> 4, m16 = lane & 15;
  const int h = blockIdx.y, b = blockIdx.z;
  const size_t base = (size_t)b * 2048 * 1024 + (size_t)h * 64;
  const size_t vbase = (size_t)(h * 64) * 4096 + (size_t)b * 2048;
  const float SC = 0.03125f * LOG2E;
  const f32x4 z4 = {0.f, 0.f, 0.f, 0.f};

  // staging role: 128 threads per array; each thread owns 64B of one row.
  const int sarr = tid >> 7;            // 0:K0 1:V0 2:K1 3:V1
  const int su = tid & 127;
  const int sr = su >> 1, sh = (su & 1) * 32;
  const int stileoff = sarr >> 1;       // tile parity this role stages
  const bool skrole = (sarr & 1) == 0;  // K vs V source
  u16* const sdst = (sarr == 0) ? &Ks[0] : (sarr == 1) ? &Vs[0]
                  : (sarr == 2) ? &Ks[64 * 72] : &Vs[64 * 72];

  const int lbase = grp * (64 * 72);    // this group's Ks/Vs/Ps offset

  for (int pass = 0; pass < 2; ++pass) {
    const int qt = pass == 0 ? (int)blockIdx.x : 31 - (int)blockIdx.x;
    const int q0 = qt * 64;

    // ---- Q A-frags direct from global + fused RoPE (once per pass) ----
    const int trow = q0 + wl * 16 + m16;
    bf16x8 qf[2];
    {
      const u16* qp = &qg[base + (size_t)trow * 1024 + quad * 8];
      u16x8 qraw[2];
      qraw[0] = *(const u16x8*)qp;
      qraw[1] = *(const u16x8*)(qp + 32);
#pragma unroll
      for (int f = 0; f < 2; f++) {
        u16x8 o;
#pragma unroll
        for (int p = 0; p < 4; p++) {
          const float a0 = bf2f(qraw[f][2 * p]);
          const float a1 = bf2f(qraw[f][2 * p + 1]);
          const int i = f * 16 + quad * 4 + p;
          const float th = exp2f(-(float)i * 0.02595256324130752f);
          float s, c;
          sincosf((float)trow * th, &s, &c);
          o[2 * p]     = f2bf(a0 * c - a1 * s);
          o[2 * p + 1] = f2bf(a1 * c + a0 * s);
        }
        qf[f] = *(bf16x8*)&o;
      }
    }

    // initial prefetch of tiles {0,1} for this pass
    u16x8 pr[4];
    {
      const int tile = stileoff;
      if (tile <= qt) {
        if (skrole) {
          const u16* s = &kg[base + (size_t)(tile * 64 + sr) * 1024 + sh];
#pragma unroll
          for (int j = 0; j < 4; j++) pr[j] = *(const u16x8*)(s + j * 8);
        } else {
          const u16* s = &vt[vbase + (size_t)sr * 4096 + tile * 64 + sh];
#pragma unroll
          for (int j = 0; j < 4; j++) pr[j] = *(const u16x8*)(s + j * 8);
        }
      }
    }

    float l_p[4] = {0.f, 0.f, 0.f, 0.f};
    f32x4 O[4];
#pragma unroll
    for (int d = 0; d < 4; d++) O[d] = z4;

    const int qrow0 = q0 + wl * 16 + quad * 4;

    for (int kt0 = 0; kt0 <= qt; kt0 += 2) {
      __syncthreads();  // prior reads of Ks/Vs/Ps (or epilogue) complete
#pragma unroll
      for (int j = 0; j < 4; j++)
        *(u16x8*)&sdst[sr * 72 + sh + j * 8] = pr[j];
      __syncthreads();

      {  // prefetch next super-iter's tile for my role
        const int tile = kt0 + 2 + stileoff;
        if (tile <= qt) {
          if (skrole) {
            const u16* s = &kg[base + (size_t)(tile * 64 + sr) * 1024 + sh];
#pragma unroll
            for (int j = 0; j < 4; j++) pr[j] = *(const u16x8*)(s + j * 8);
          } else {
            const u16* s = &vt[vbase + (size_t)sr * 4096 + tile * 64 + sh];
#pragma unroll
            for (int j = 0; j < 4; j++) pr[j] = *(const u16x8*)(s + j * 8);
          }
        }
      }

      const int ktg = kt0 + grp;
      if (ktg <= qt) {
        const int k0 = ktg * 64;

        // S = Q K^T
        f32x4 S[4];
#pragma unroll
        for (int nt = 0; nt < 4; nt++) {
          const bf16x8 kf0 =
              *(const bf16x8*)&Ks[lbase + (nt * 16 + m16) * 72 + quad * 8];
          const bf16x8 kf1 =
              *(const bf16x8*)&Ks[lbase + (nt * 16 + m16) * 72 + 32 + quad * 8];
          S[nt] = __builtin_amdgcn_mfma_f32_16x16x32_bf16(qf[0], kf0, z4, 0, 0, 0);
          S[nt] = __builtin_amdgcn_mfma_f32_16x16x32_bf16(qf[1], kf1, S[nt], 0, 0, 0);
        }

        const bool diag = (ktg == qt);
#pragma unroll
        for (int nt = 0; nt < 4; nt++) {
          const int key = k0 + nt * 16 + m16;
#pragma unroll
          for (int r = 0; r < 4; r++) {
            float p = exp2f(S[nt][r] * SC);
            if (diag && key > qrow0 + r) p = 0.f;
            union { float f; uint32_t i; } u; u.f = p;
            const uint32_t hi = u.i & 0xffff0000u;  // RTZ bf16
            Ps[lbase + (wl * 16 + quad * 4 + r) * 72 + nt * 16 + m16] =
                (u16)(hi >> 16);
            union { uint32_t i; float f; } pf_; pf_.i = hi;
            l_p[r] += pf_.f;
          }
        }

        // O += P V (Ps rows wave-local; Vs fenced by stage barrier)
        const bf16x8 pf0 =
            *(const bf16x8*)&Ps[lbase + (wl * 16 + m16) * 72 + quad * 8];
        const bf16x8 pf1 =
            *(const bf16x8*)&Ps[lbase + (wl * 16 + m16) * 72 + 32 + quad * 8];
#pragma unroll
        for (int dt = 0; dt < 4; dt++) {
          const bf16x8 vf0 =
              *(const bf16x8*)&Vs[lbase + (dt * 16 + m16) * 72 + quad * 8];
          const bf16x8 vf1 =
              *(const bf16x8*)&Vs[lbase + (dt * 16 + m16) * 72 + 32 + quad * 8];
          O[dt] = __builtin_amdgcn_mfma_f32_16x16x32_bf16(pf0, vf0, O[dt], 0, 0, 0);
          O[dt] = __builtin_amdgcn_mfma_f32_16x16x32_bf16(pf1, vf1, O[dt], 0, 0, 0);
        }
      }
    }

    // ---- combine groups: O = O_A + O_B, l = l_A + l_B (additive) ----
#pragma unroll
    for (int off = 1; off < 16; off <<= 1)
#pragma unroll
      for (int r = 0; r < 4; r++) l_p[r] += __shfl_xor(l_p[r], off);

    __syncthreads();  // all compute reads of Ks/Vs done
    float* const Osh = (float*)Ks;  // 64 x 65 f32 (stride-65: bank spread)
    float* const Lsh = (float*)Vs;  // 64 f32
    if (grp == 1) {
#pragma unroll
      for (int dt = 0; dt < 4; dt++)
#pragma unroll
        for (int r = 0; r < 4; r++)
          Osh[(wl * 16 + quad * 4 + r) * 65 + dt * 16 + m16] = O[dt][r];
#pragma unroll
      for (int r = 0; r < 4; r++)
        Lsh[wl * 16 + quad * 4 + r] = l_p[r];  // same-value multi-write, ok
    }
    __syncthreads();
    if (grp == 0) {
      float inv[4];
#pragma unroll
      for (int r = 0; r < 4; r++)
        inv[r] = 1.0f / (l_p[r] + Lsh[wl * 16 + quad * 4 + r]);
#pragma unroll
      for (int dt = 0; dt < 4; dt++)
#pragma unroll
        for (int r = 0; r < 4; r++) {
          const float o =
              O[dt][r] + Osh[(wl * 16 + quad * 4 + r) * 65 + dt * 16 + m16];
          out[base + (size_t)(qrow0 + r) * 1024 + dt * 16 + m16] = o * inv[r];
        }
    }
  }
}

extern "C" void kernel_launch(void* const* d_in, const int* in_sizes, int n_in,
                              void* d_out, int out_size, void* d_ws, size_t ws_size,
                              hipStream_t stream) {
  const float* x  = (const float*)d_in[0];
  const float* Wq = (const float*)d_in[1];
  const float* Wk = (const float*)d_in[2];
  const float* Wv = (const float*)d_in[3];
  u16* qb  = (u16*)d_ws;                    // [4096][1024] bf16
  u16* kb  = qb  + (size_t)4096 * 1024;     // [4096][1024] bf16
  u16* vtw = kb  + (size_t)4096 * 1024;     // [1024][4096] bf16 (V^T)
  u16* xc  = vtw + (size_t)4096 * 1024;     // bf16 inputs
  u16* wqc = xc  + (size_t)4096 * 1024;
  u16* wkc = wqc + (size_t)1024 * 1024;
  u16* wvc = wkc + (size_t)1024 * 1024;

  f32_to_bf16<<<dim3(2048, 4), 256, 0, stream>>>(x, Wq, Wk, Wv,
                                                 xc, wqc, wkc, wvc);
  qkv_gemm<<<dim3(8, 32, 3), 256, 0, stream>>>(xc, wqc, wkc, wvc,
                                               qb, kb, vtw);
  rope_inplace_k<<<dim3(8192), 256, 0, stream>>>(kb);
  flash_attn<<<dim3(16, 16, 2), 512, 0, stream>>>(qb, kb, vtw, (float*)d_out);
}